// Round 2
// baseline (406.232 us; speedup 1.0000x reference)
//
#include <hip/hip_runtime.h>
#include <hip/hip_fp16.h>

// Problem constants (match reference)
#define T_DIM 64
#define K_DIM 8192
#define N_DIM 8192
#define KSPLIT 16
#define KC (K_DIM / KSPLIT)   // 512 k per block
#define BN 128                // output channels per block

typedef __fp16 half8_t __attribute__((ext_vector_type(8)));
typedef __fp16 half4_t __attribute__((ext_vector_type(4)));
typedef __fp16 half2_t __attribute__((ext_vector_type(2)));
typedef float  f32x4   __attribute__((ext_vector_type(4)));
typedef int    i32x4   __attribute__((ext_vector_type(4)));

// Kernel 1: convert x (f32) -> xh (f16), and compute rowsum[t] = sum_k (f16-rounded x)
// One block per token row.
__global__ __launch_bounds__(256) void prep_kernel(const float* __restrict__ x,
                                                   __fp16* __restrict__ xh,
                                                   float* __restrict__ rowsum) {
    const int t = blockIdx.x;
    const float* xr = x + (size_t)t * K_DIM;
    __fp16* xhr = xh + (size_t)t * K_DIM;
    float s = 0.0f;
    for (int k = threadIdx.x * 4; k < K_DIM; k += 256 * 4) {
        f32x4 v = *(const f32x4*)(xr + k);
        half4_t h;
        h[0] = (__fp16)v[0]; h[1] = (__fp16)v[1];
        h[2] = (__fp16)v[2]; h[3] = (__fp16)v[3];
        *(half4_t*)(xhr + k) = h;
        s += (float)h[0] + (float)h[1] + (float)h[2] + (float)h[3];
    }
    #pragma unroll
    for (int off = 32; off > 0; off >>= 1) s += __shfl_down(s, off, 64);
    __shared__ float red[4];
    const int lane = threadIdx.x & 63;
    const int w = threadIdx.x >> 6;
    if (lane == 0) red[w] = s;
    __syncthreads();
    if (threadIdx.x == 0) rowsum[t] = red[0] + red[1] + red[2] + red[3];
}

// Kernel 2: S[t,o] = sum_k xh[t,k] * q[o,k] via f16 MFMA on raw codes.
// Epilogue: atomicAdd( scale[o]*S  + once(bias[o] - scale[o]*zp[o]*rowsum[t]) ).
// Grid: (N/BN) x KSPLIT. Block: 256 threads = 4 waves; each wave owns 32 channels.
__global__ __launch_bounds__(256, 4) void woq_gemm_kernel(
        const int* __restrict__ qw, const __fp16* __restrict__ xh,
        const float* __restrict__ rowsum, const float* __restrict__ scales,
        const int* __restrict__ zps, const float* __restrict__ bias,
        float* __restrict__ out) {
    const int bx = blockIdx.x;        // N block (64)
    const int bz = blockIdx.y;        // K chunk (KSPLIT)
    const int tid = threadIdx.x;
    const int wid = __builtin_amdgcn_readfirstlane(tid >> 6);
    const int lane = tid & 63;
    const int r = lane & 15;          // fragment row/col index
    const int g = lane >> 4;          // k-group (0..3)

    const int n_wave = bx * BN + wid * 32;   // this wave's channel base
    const int k0 = bz * KC;

    // A frag base: token row r, k-offset g*8 (8 consecutive f16 = 16B per lane)
    const __fp16* aptr = xh + (size_t)r * K_DIM + k0 + g * 8;
    // B frag base: channel row (n_wave + r), 8 consecutive int32 = 32B per lane
    const int* bptr = qw + (size_t)(n_wave + r) * K_DIM + k0 + g * 8;

    f32x4 acc[4][2] = {};   // 4 m-tiles (64 tokens) x 2 n-tiles (32 channels)

    #pragma unroll 2
    for (int kk = 0; kk < KC; kk += 32) {
        half8_t af[4];
        #pragma unroll
        for (int m = 0; m < 4; ++m)
            af[m] = *(const half8_t*)(aptr + (size_t)m * 16 * K_DIM + kk);

        half8_t bf[2];
        #pragma unroll
        for (int n = 0; n < 2; ++n) {
            const int* bp = bptr + (size_t)n * 16 * K_DIM + kk;
            i32x4 q0 = *(const i32x4*)bp;
            i32x4 q1 = *(const i32x4*)(bp + 4);
            union { half8_t h8; half2_t h2[4]; } u;
            u.h2[0] = __builtin_amdgcn_cvt_pkrtz((float)q0[0], (float)q0[1]);
            u.h2[1] = __builtin_amdgcn_cvt_pkrtz((float)q0[2], (float)q0[3]);
            u.h2[2] = __builtin_amdgcn_cvt_pkrtz((float)q1[0], (float)q1[1]);
            u.h2[3] = __builtin_amdgcn_cvt_pkrtz((float)q1[2], (float)q1[3]);
            bf[n] = u.h8;
        }

        #pragma unroll
        for (int m = 0; m < 4; ++m)
            #pragma unroll
            for (int n = 0; n < 2; ++n)
                acc[m][n] = __builtin_amdgcn_mfma_f32_16x16x32_f16(af[m], bf[n], acc[m][n], 0, 0, 0);
    }

    // Epilogue. D layout (verified, m89): row(M) = m*16 + g*4 + j, col(N) = n*16 + r.
    #pragma unroll
    for (int n = 0; n < 2; ++n) {
        const int c = n_wave + n * 16 + r;
        const float sc = scales[c];
        const float szp = sc * (float)zps[c];
        const float bv = bias[c];
        #pragma unroll
        for (int m = 0; m < 4; ++m) {
            #pragma unroll
            for (int j = 0; j < 4; ++j) {
                const int t = m * 16 + g * 4 + j;
                float val = sc * acc[m][n][j];
                if (bz == 0) val += bv - szp * rowsum[t];   // rank-1 correction + bias, added once
                atomicAdd(&out[(size_t)t * N_DIM + c], val);
            }
        }
    }
}

extern "C" void kernel_launch(void* const* d_in, const int* in_sizes, int n_in,
                              void* d_out, int out_size, void* d_ws, size_t ws_size,
                              hipStream_t stream) {
    const float* x      = (const float*)d_in[0];
    const int*   qw     = (const int*)d_in[1];
    const float* scales = (const float*)d_in[2];
    const int*   zps    = (const int*)d_in[3];
    const float* bias   = (const float*)d_in[4];
    float* out = (float*)d_out;

    __fp16* xh  = (__fp16*)d_ws;                                            // 1 MiB
    float* rowsum = (float*)((char*)d_ws + (size_t)T_DIM * K_DIM * sizeof(__fp16));

    (void)hipMemsetAsync(d_out, 0, (size_t)out_size * sizeof(float), stream);
    prep_kernel<<<T_DIM, 256, 0, stream>>>(x, xh, rowsum);
    woq_gemm_kernel<<<dim3(N_DIM / BN, KSPLIT), 256, 0, stream>>>(
        qw, xh, rowsum, scales, zps, bias, out);
}

// Round 3
// 389.426 us; speedup vs baseline: 1.0432x; 1.0432x over previous
//
#include <hip/hip_runtime.h>
#include <hip/hip_fp16.h>

// Problem constants (match reference)
#define T_DIM 64
#define K_DIM 8192
#define N_DIM 8192
#define KSPLIT 16
#define KC (K_DIM / KSPLIT)   // 512 k per K-chunk block
#define BN 128                // output channels per block
#define NBX (N_DIM / BN)      // 64 N-blocks

typedef __fp16 half8_t __attribute__((ext_vector_type(8)));
typedef __fp16 half4_t __attribute__((ext_vector_type(4)));
typedef __fp16 half2_t __attribute__((ext_vector_type(2)));
typedef float  f32x4   __attribute__((ext_vector_type(4)));
typedef int    i32x4   __attribute__((ext_vector_type(4)));

// ---------------------------------------------------------------------------
// Kernel 1: x (f32) -> xh (f16); rowsum partials (f16-rounded, per quarter-row).
// 256 blocks: block = (token t, quarter q). Each thread converts 8 elements.
__global__ __launch_bounds__(256) void prep_kernel(const float* __restrict__ x,
                                                   __fp16* __restrict__ xh,
                                                   float* __restrict__ rowsum_part) {
    const int t = blockIdx.x >> 2;
    const int q = blockIdx.x & 3;
    const int kbase = q * (K_DIM / 4) + threadIdx.x * 8;
    const float* xr = x + (size_t)t * K_DIM + kbase;
    __fp16* xhr = xh + (size_t)t * K_DIM + kbase;

    f32x4 v0 = *(const f32x4*)xr;
    f32x4 v1 = *(const f32x4*)(xr + 4);
    half8_t h;
    h[0] = (__fp16)v0[0]; h[1] = (__fp16)v0[1]; h[2] = (__fp16)v0[2]; h[3] = (__fp16)v0[3];
    h[4] = (__fp16)v1[0]; h[5] = (__fp16)v1[1]; h[6] = (__fp16)v1[2]; h[7] = (__fp16)v1[3];
    *(half8_t*)xhr = h;

    float s = 0.0f;
    #pragma unroll
    for (int i = 0; i < 8; ++i) s += (float)h[i];

    #pragma unroll
    for (int off = 32; off > 0; off >>= 1) s += __shfl_down(s, off, 64);
    __shared__ float red[4];
    const int lane = threadIdx.x & 63;
    const int w = threadIdx.x >> 6;
    if (lane == 0) red[w] = s;
    __syncthreads();
    if (threadIdx.x == 0) rowsum_part[t * 4 + q] = red[0] + red[1] + red[2] + red[3];
}

// ---------------------------------------------------------------------------
// Kernel 2: raw partial S[t,o] = sum_{k in chunk} xh[t,k]*q[o,k] via f16 MFMA.
// NO atomics: each block stores its 64x128 partial tile into a wave-private,
// perfectly-coalesced region of d_ws. Grid: (NBX, KSPLIT). 256 thr = 4 waves.
__global__ __launch_bounds__(256, 4) void woq_gemm_kernel(
        const int* __restrict__ qw, const __fp16* __restrict__ xh,
        float* __restrict__ part) {
    const int bx = blockIdx.x;        // N block (64)
    const int bz = blockIdx.y;        // K chunk (KSPLIT)
    const int tid = threadIdx.x;
    const int wid = __builtin_amdgcn_readfirstlane(tid >> 6);
    const int lane = tid & 63;
    const int r = lane & 15;          // fragment row/col index
    const int g = lane >> 4;          // k-group (0..3)

    const int n_wave = bx * BN + wid * 32;   // this wave's channel base
    const int k0 = bz * KC;

    // A frag base: token row r, k-offset g*8 (16B per lane)
    const __fp16* aptr = xh + (size_t)r * K_DIM + k0 + g * 8;
    // B frag base: channel row (n_wave + r), 32B per lane
    const int* bptr = qw + (size_t)(n_wave + r) * K_DIM + k0 + g * 8;

    f32x4 acc[4][2] = {};   // 4 m-tiles (64 tokens) x 2 n-tiles (32 channels)

    #pragma unroll 2
    for (int kk = 0; kk < KC; kk += 32) {
        half8_t af[4];
        #pragma unroll
        for (int m = 0; m < 4; ++m)
            af[m] = *(const half8_t*)(aptr + (size_t)m * 16 * K_DIM + kk);

        half8_t bf[2];
        #pragma unroll
        for (int n = 0; n < 2; ++n) {
            const int* bp = bptr + (size_t)n * 16 * K_DIM + kk;
            i32x4 q0 = *(const i32x4*)bp;
            i32x4 q1 = *(const i32x4*)(bp + 4);
            union { half8_t h8; half2_t h2[4]; } u;
            u.h2[0] = __builtin_amdgcn_cvt_pkrtz((float)q0[0], (float)q0[1]);
            u.h2[1] = __builtin_amdgcn_cvt_pkrtz((float)q0[2], (float)q0[3]);
            u.h2[2] = __builtin_amdgcn_cvt_pkrtz((float)q1[0], (float)q1[1]);
            u.h2[3] = __builtin_amdgcn_cvt_pkrtz((float)q1[2], (float)q1[3]);
            bf[n] = u.h8;
        }

        #pragma unroll
        for (int m = 0; m < 4; ++m)
            #pragma unroll
            for (int n = 0; n < 2; ++n)
                acc[m][n] = __builtin_amdgcn_mfma_f32_16x16x32_f16(af[m], bf[n], acc[m][n], 0, 0, 0);
    }

    // Store raw partials, wave-private layout:
    //   part[((bz*NBX + bx)*4 + wid)*2048 + ((n*4+m)*4+j)*64 + g*16 + r]
    // Each store instruction writes 256B contiguous (64 lanes x 4B).
    float* pp = part + (((size_t)bz * NBX + bx) * 4 + wid) * 2048 + g * 16 + r;
    #pragma unroll
    for (int n = 0; n < 2; ++n)
        #pragma unroll
        for (int m = 0; m < 4; ++m)
            #pragma unroll
            for (int j = 0; j < 4; ++j)
                pp[((n * 4 + m) * 4 + j) * 64] = acc[m][n][j];
}

// ---------------------------------------------------------------------------
// Kernel 3: sum KSPLIT partials, apply scale/zero-point/bias, write out.
// y[t,c] = scale[c]*S[t,c] - scale[c]*zp[c]*rowsum[t] + bias[c]
// 2048 blocks x 256 threads; each thread handles 4 consecutive channels.
__global__ __launch_bounds__(256) void reduce_kernel(
        const float* __restrict__ part, const float* __restrict__ rowsum_part,
        const float* __restrict__ scales, const int* __restrict__ zps,
        const float* __restrict__ bias, float* __restrict__ out) {
    const int idx = blockIdx.x * 256 + threadIdx.x;
    const int e = idx * 4;            // flat output index
    const int t = e >> 13;            // / 8192
    const int c = e & (N_DIM - 1);
    const int bx = c >> 7;
    const int wid = (c >> 5) & 3;
    const int n = (c >> 4) & 1;
    const int r0 = c & 15;            // 0,4,8,12
    const int m = t >> 4;
    const int g = (t >> 2) & 3;
    const int j = t & 3;

    const size_t off = ((size_t)bx * 4 + wid) * 2048 + ((n * 4 + m) * 4 + j) * 64 + g * 16 + r0;
    f32x4 s = {0.f, 0.f, 0.f, 0.f};
    #pragma unroll
    for (int bz = 0; bz < KSPLIT; ++bz)
        s += *(const f32x4*)(part + (size_t)bz * (NBX * 4 * 2048) + off);

    const float rs = rowsum_part[t * 4 + 0] + rowsum_part[t * 4 + 1] +
                     rowsum_part[t * 4 + 2] + rowsum_part[t * 4 + 3];

    f32x4 sc = *(const f32x4*)(scales + c);
    i32x4 zp = *(const i32x4*)(zps + c);
    f32x4 bv = *(const f32x4*)(bias + c);
    f32x4 y;
    #pragma unroll
    for (int i = 0; i < 4; ++i)
        y[i] = sc[i] * (s[i] - (float)zp[i] * rs) + bv[i];
    *(f32x4*)(out + e) = y;
}

// ---------------------------------------------------------------------------
extern "C" void kernel_launch(void* const* d_in, const int* in_sizes, int n_in,
                              void* d_out, int out_size, void* d_ws, size_t ws_size,
                              hipStream_t stream) {
    const float* x      = (const float*)d_in[0];
    const int*   qw     = (const int*)d_in[1];
    const float* scales = (const float*)d_in[2];
    const int*   zps    = (const int*)d_in[3];
    const float* bias   = (const float*)d_in[4];
    float* out = (float*)d_out;

    // Workspace layout: xh (1 MiB) | rowsum_part (1 KiB) | partials (32 MiB, at 2 MiB)
    __fp16* xh          = (__fp16*)d_ws;
    float*  rowsum_part = (float*)((char*)d_ws + (size_t)T_DIM * K_DIM * sizeof(__fp16));
    float*  part        = (float*)((char*)d_ws + (2u << 20));

    prep_kernel<<<256, 256, 0, stream>>>(x, xh, rowsum_part);
    woq_gemm_kernel<<<dim3(NBX, KSPLIT), 256, 0, stream>>>(qw, xh, part);
    reduce_kernel<<<(T_DIM * N_DIM / 4) / 256, 256, 0, stream>>>(
        part, rowsum_part, scales, zps, bias, out);
}